// Round 2
// baseline (63.032 us; speedup 1.0000x reference)
//
#include <hip/hip_runtime.h>

#define NE 30
#define NB 2          // boxes per cell
#define NCELL (4096 * 196)
#define CELLS_PER_BLOCK 256
#define FLOATS_PER_BLOCK (CELLS_PER_BLOCK * NE)   // 7680
#define VEC4_PER_BLOCK (FLOATS_PER_BLOCK / 4)     // 1920
#define LAMBDA_COORD 5.0f
#define LAMBDA_NOOBJ 0.5f
#define EPSF 1e-12f

__global__ __launch_bounds__(256) void yolo_loss_kernel(
    const float* __restrict__ pred,
    const float* __restrict__ tgt,
    float* __restrict__ out)
{
    __shared__ float sp[FLOATS_PER_BLOCK];
    __shared__ float st[FLOATS_PER_BLOCK];

    const int tid = threadIdx.x;
    const size_t blockFloatBase = (size_t)blockIdx.x * FLOATS_PER_BLOCK;

    // ---- coalesced staging: global float4 -> LDS ----
    {
        const float4* gp = reinterpret_cast<const float4*>(pred + blockFloatBase);
        const float4* gt = reinterpret_cast<const float4*>(tgt  + blockFloatBase);
        float4* sp4 = reinterpret_cast<float4*>(sp);
        float4* st4 = reinterpret_cast<float4*>(st);
        #pragma unroll
        for (int k = tid; k < VEC4_PER_BLOCK; k += 256) {
            sp4[k] = gp[k];
            st4[k] = gt[k];
        }
    }
    __syncthreads();

    // ---- per-cell compute from LDS ----
    const float* p = sp + tid * NE;
    const float* t = st + tid * NE;

    const float coord = (t[5] > 0.0f)  ? 1.0f : 0.0f;
    const float noobj = (t[5] == 0.0f) ? 1.0f : 0.0f;

    // class loss: indices 10..29
    float cls = 0.0f;
    #pragma unroll
    for (int k = NB * 5; k < NE; ++k) {
        float d = p[k] - t[k];
        cls += d * d;
    }
    cls *= coord;

    // confidence squared-diffs
    float dconf0 = p[4] - t[4];
    float dconf1 = p[9] - t[9];
    float conf_sq0 = dconf0 * dconf0;
    float conf_sq1 = dconf1 * dconf1;
    float no = noobj * (conf_sq0 + conf_sq1);

    // corners + areas
    float c1[NB][4], c2[NB][4], a1[NB], a2[NB];
    #pragma unroll
    for (int i = 0; i < NB; ++i) {
        float x = p[i*5 + 0], y = p[i*5 + 1];
        float w2 = p[i*5 + 2] * p[i*5 + 2];
        float h2 = p[i*5 + 3] * p[i*5 + 3];
        c1[i][0] = x - w2; c1[i][1] = y - h2;
        c1[i][2] = x + w2; c1[i][3] = y + h2;
        a1[i] = (2.0f * w2) * (2.0f * h2);

        float tx = t[i*5 + 0], ty = t[i*5 + 1];
        float tw2 = t[i*5 + 2] * t[i*5 + 2];
        float th2 = t[i*5 + 3] * t[i*5 + 3];
        c2[i][0] = tx - tw2; c2[i][1] = ty - th2;
        c2[i][2] = tx + tw2; c2[i][3] = ty + th2;
        a2[i] = (2.0f * tw2) * (2.0f * th2);
    }

    // IoU matrix [pred i][tgt j]
    float iou[NB][NB];
    #pragma unroll
    for (int i = 0; i < NB; ++i) {
        #pragma unroll
        for (int j = 0; j < NB; ++j) {
            float tlx = fmaxf(c1[i][0], c2[j][0]);
            float tly = fmaxf(c1[i][1], c2[j][1]);
            float brx = fminf(c1[i][2], c2[j][2]);
            float bry = fminf(c1[i][3], c2[j][3]);
            float wx = fmaxf(brx - tlx, 0.0f);
            float wy = fmaxf(bry - tly, 0.0f);
            float inter = wx * wy;
            float uni = a1[i] + a2[j] - inter;
            iou[i][j] = inter / fmaxf(uni, EPSF);
        }
    }

    // argmax over pred axis, first-index tie-break
    bool m0 = iou[1][0] > iou[0][0];
    bool m1 = iou[1][1] > iou[0][1];
    float w0 = coord * ((!m0 || !m1) ? 1.0f : 0.0f);
    float w1 = coord * (( m0 ||  m1) ? 1.0f : 0.0f);

    float contain = w0 * conf_sq0 + w1 * conf_sq1;

    float loc0 = 0.0f, loc1 = 0.0f;
    #pragma unroll
    for (int k = 0; k < 4; ++k) {
        float d0 = p[k] - t[k];
        float d1 = p[5 + k] - t[5 + k];
        loc0 += d0 * d0;
        loc1 += d1 * d1;
    }
    float loc = w0 * loc0 + w1 * loc1;

    float cell = LAMBDA_COORD * loc + contain + LAMBDA_NOOBJ * no + cls;

    // ---- reduction: wave shuffle -> LDS -> atomic ----
    #pragma unroll
    for (int off = 32; off > 0; off >>= 1)
        cell += __shfl_down(cell, off, 64);

    __shared__ float wsum[4];
    const int lane = tid & 63;
    const int wid  = tid >> 6;
    if (lane == 0) wsum[wid] = cell;
    __syncthreads();
    if (tid == 0) {
        float s = wsum[0] + wsum[1] + wsum[2] + wsum[3];
        atomicAdd(out, s);
    }
}

extern "C" void kernel_launch(void* const* d_in, const int* in_sizes, int n_in,
                              void* d_out, int out_size, void* d_ws, size_t ws_size,
                              hipStream_t stream) {
    const float* pred = (const float*)d_in[0];
    const float* tgt  = (const float*)d_in[1];
    float* out = (float*)d_out;

    hipMemsetAsync(out, 0, sizeof(float) * out_size, stream);

    const int grid = NCELL / CELLS_PER_BLOCK;   // 3136
    hipLaunchKernelGGL(yolo_loss_kernel, dim3(grid), dim3(256), 0, stream,
                       pred, tgt, out);
}

// Round 3
// 45.744 us; speedup vs baseline: 1.3779x; 1.3779x over previous
//
#include <hip/hip_runtime.h>
#include <stdint.h>

#define NE 30
#define NB 2
#define NCELL (4096 * 196)          // 802816
#define CPB 64                      // cells per block == threads per block (1 wave)
#define NBLK (NCELL / CPB)          // 12544 (exact)
#define PRED_F4 (CPB * NE / 4)      // 480 float4 of pred per block
#define TOT_F4 (2 * PRED_F4)        // 960 float4 total per block
#define NSTAGE (TOT_F4 / 64)        // 15 global_load_lds instrs per wave
#define LAMBDA_COORD 5.0f
#define LAMBDA_NOOBJ 0.5f
#define EPSF 1e-12f

__global__ __launch_bounds__(64) void yolo_cell_kernel(
    const float* __restrict__ pred,
    const float* __restrict__ tgt,
    float* __restrict__ partial)
{
    // [0,1920) = pred floats for 64 cells, [1920,3840) = tgt floats
    __shared__ float sbuf[2 * CPB * NE];   // 15360 B

    const int lane = threadIdx.x;          // 0..63
    const int blk  = blockIdx.x;

    const float4* gp = reinterpret_cast<const float4*>(pred) + (size_t)blk * PRED_F4;
    const float4* gt = reinterpret_cast<const float4*>(tgt)  + (size_t)blk * PRED_F4;

    // ---- fire-and-forget staging: 15 x global_load_lds(16B) ----
    #pragma unroll
    for (int k = 0; k < NSTAGE; ++k) {
        const int f = k * 64 + lane;       // combined float4 index [0,960)
        const float4* src = (f < PRED_F4) ? (gp + f) : (gt + (f - PRED_F4));
        __builtin_amdgcn_global_load_lds(
            (const __attribute__((address_space(1))) void*)src,
            (__attribute__((address_space(3))) void*)&sbuf[k * 256],
            16, 0, 0);
    }
    __syncthreads();   // drains vmcnt, single-wave barrier is cheap

    // ---- per-cell compute from LDS ----
    const float* p = sbuf + lane * NE;
    const float* t = sbuf + CPB * NE + lane * NE;

    const float coord = (t[5] > 0.0f)  ? 1.0f : 0.0f;
    const float noobj = (t[5] == 0.0f) ? 1.0f : 0.0f;

    float cls = 0.0f;
    #pragma unroll
    for (int k = NB * 5; k < NE; ++k) {
        float d = p[k] - t[k];
        cls += d * d;
    }
    cls *= coord;

    float dconf0 = p[4] - t[4];
    float dconf1 = p[9] - t[9];
    float conf_sq0 = dconf0 * dconf0;
    float conf_sq1 = dconf1 * dconf1;
    float no = noobj * (conf_sq0 + conf_sq1);

    float c1[NB][4], c2[NB][4], a1[NB], a2[NB];
    #pragma unroll
    for (int i = 0; i < NB; ++i) {
        float x = p[i*5 + 0], y = p[i*5 + 1];
        float w2 = p[i*5 + 2] * p[i*5 + 2];
        float h2 = p[i*5 + 3] * p[i*5 + 3];
        c1[i][0] = x - w2; c1[i][1] = y - h2;
        c1[i][2] = x + w2; c1[i][3] = y + h2;
        a1[i] = (2.0f * w2) * (2.0f * h2);

        float tx = t[i*5 + 0], ty = t[i*5 + 1];
        float tw2 = t[i*5 + 2] * t[i*5 + 2];
        float th2 = t[i*5 + 3] * t[i*5 + 3];
        c2[i][0] = tx - tw2; c2[i][1] = ty - th2;
        c2[i][2] = tx + tw2; c2[i][3] = ty + th2;
        a2[i] = (2.0f * tw2) * (2.0f * th2);
    }

    float iou[NB][NB];
    #pragma unroll
    for (int i = 0; i < NB; ++i) {
        #pragma unroll
        for (int j = 0; j < NB; ++j) {
            float tlx = fmaxf(c1[i][0], c2[j][0]);
            float tly = fmaxf(c1[i][1], c2[j][1]);
            float brx = fminf(c1[i][2], c2[j][2]);
            float bry = fminf(c1[i][3], c2[j][3]);
            float wx = fmaxf(brx - tlx, 0.0f);
            float wy = fmaxf(bry - tly, 0.0f);
            float inter = wx * wy;
            float uni = a1[i] + a2[j] - inter;
            iou[i][j] = inter / fmaxf(uni, EPSF);
        }
    }

    // argmax over pred axis, first-index tie-break
    bool m0 = iou[1][0] > iou[0][0];
    bool m1 = iou[1][1] > iou[0][1];
    float w0 = coord * ((!m0 || !m1) ? 1.0f : 0.0f);
    float w1 = coord * (( m0 ||  m1) ? 1.0f : 0.0f);

    float contain = w0 * conf_sq0 + w1 * conf_sq1;

    float loc0 = 0.0f, loc1 = 0.0f;
    #pragma unroll
    for (int k = 0; k < 4; ++k) {
        float d0 = p[k] - t[k];
        float d1 = p[5 + k] - t[5 + k];
        loc0 += d0 * d0;
        loc1 += d1 * d1;
    }
    float loc = w0 * loc0 + w1 * loc1;

    float cell = LAMBDA_COORD * loc + contain + LAMBDA_NOOBJ * no + cls;

    // ---- single-wave shuffle reduction -> one partial per block ----
    #pragma unroll
    for (int off = 32; off > 0; off >>= 1)
        cell += __shfl_down(cell, off, 64);

    if (lane == 0) partial[blk] = cell;
}

__global__ __launch_bounds__(256) void yolo_reduce_kernel(
    const float* __restrict__ partial,
    float* __restrict__ out)
{
    const int tid = threadIdx.x;
    float s = 0.0f;
    for (int i = tid; i < NBLK; i += 256)   // 12544 = 49 * 256, exact
        s += partial[i];

    #pragma unroll
    for (int off = 32; off > 0; off >>= 1)
        s += __shfl_down(s, off, 64);

    __shared__ float wsum[4];
    const int lane = tid & 63;
    const int wid  = tid >> 6;
    if (lane == 0) wsum[wid] = s;
    __syncthreads();
    if (tid == 0)
        out[0] = wsum[0] + wsum[1] + wsum[2] + wsum[3];
}

extern "C" void kernel_launch(void* const* d_in, const int* in_sizes, int n_in,
                              void* d_out, int out_size, void* d_ws, size_t ws_size,
                              hipStream_t stream) {
    const float* pred = (const float*)d_in[0];
    const float* tgt  = (const float*)d_in[1];
    float* out = (float*)d_out;
    float* partial = (float*)d_ws;          // 12544 floats = 50 KB scratch

    hipLaunchKernelGGL(yolo_cell_kernel, dim3(NBLK), dim3(64), 0, stream,
                       pred, tgt, partial);
    hipLaunchKernelGGL(yolo_reduce_kernel, dim3(1), dim3(256), 0, stream,
                       partial, out);
}

// Round 4
// 36.864 us; speedup vs baseline: 1.7098x; 1.2409x over previous
//
#include <hip/hip_runtime.h>
#include <stdint.h>

#define NE 30
#define NB 2
#define NCELL (4096 * 196)          // 802816
#define CPB 64                      // cells per group == lanes per block (1 wave)
#define PRED_F4 (CPB * NE / 4)      // 480 float4 of pred per group
#define NSTAGE (2 * PRED_F4 / 64)   // 15 global_load_lds instrs per group
#define GPB 8                       // groups per block
#define GRID (NCELL / (CPB * GPB))  // 1568 blocks, exact
#define GROUP_FLOATS (2 * CPB * NE) // 3840 floats = 15360 B per buffer
#define LAMBDA_COORD 5.0f
#define LAMBDA_NOOBJ 0.5f
#define EPSF 1e-12f

__device__ __forceinline__ float cell_loss(const float* __restrict__ p,
                                           const float* __restrict__ t)
{
    const float coord = (t[5] > 0.0f)  ? 1.0f : 0.0f;
    const float noobj = (t[5] == 0.0f) ? 1.0f : 0.0f;

    float cls = 0.0f;
    #pragma unroll
    for (int k = NB * 5; k < NE; ++k) {
        float d = p[k] - t[k];
        cls += d * d;
    }
    cls *= coord;

    float dconf0 = p[4] - t[4];
    float dconf1 = p[9] - t[9];
    float conf_sq0 = dconf0 * dconf0;
    float conf_sq1 = dconf1 * dconf1;
    float no = noobj * (conf_sq0 + conf_sq1);

    float c1[NB][4], c2[NB][4], a1[NB], a2[NB];
    #pragma unroll
    for (int i = 0; i < NB; ++i) {
        float x = p[i*5 + 0], y = p[i*5 + 1];
        float w2 = p[i*5 + 2] * p[i*5 + 2];
        float h2 = p[i*5 + 3] * p[i*5 + 3];
        c1[i][0] = x - w2; c1[i][1] = y - h2;
        c1[i][2] = x + w2; c1[i][3] = y + h2;
        a1[i] = (2.0f * w2) * (2.0f * h2);

        float tx = t[i*5 + 0], ty = t[i*5 + 1];
        float tw2 = t[i*5 + 2] * t[i*5 + 2];
        float th2 = t[i*5 + 3] * t[i*5 + 3];
        c2[i][0] = tx - tw2; c2[i][1] = ty - th2;
        c2[i][2] = tx + tw2; c2[i][3] = ty + th2;
        a2[i] = (2.0f * tw2) * (2.0f * th2);
    }

    float iou[NB][NB];
    #pragma unroll
    for (int i = 0; i < NB; ++i) {
        #pragma unroll
        for (int j = 0; j < NB; ++j) {
            float tlx = fmaxf(c1[i][0], c2[j][0]);
            float tly = fmaxf(c1[i][1], c2[j][1]);
            float brx = fminf(c1[i][2], c2[j][2]);
            float bry = fminf(c1[i][3], c2[j][3]);
            float wx = fmaxf(brx - tlx, 0.0f);
            float wy = fmaxf(bry - tly, 0.0f);
            float inter = wx * wy;
            float uni = a1[i] + a2[j] - inter;
            iou[i][j] = inter / fmaxf(uni, EPSF);
        }
    }

    // argmax over pred axis, first-index tie-break
    bool m0 = iou[1][0] > iou[0][0];
    bool m1 = iou[1][1] > iou[0][1];
    float w0 = coord * ((!m0 || !m1) ? 1.0f : 0.0f);
    float w1 = coord * (( m0 ||  m1) ? 1.0f : 0.0f);

    float contain = w0 * conf_sq0 + w1 * conf_sq1;

    float loc0 = 0.0f, loc1 = 0.0f;
    #pragma unroll
    for (int k = 0; k < 4; ++k) {
        float d0 = p[k] - t[k];
        float d1 = p[5 + k] - t[5 + k];
        loc0 += d0 * d0;
        loc1 += d1 * d1;
    }
    float loc = w0 * loc0 + w1 * loc1;

    return LAMBDA_COORD * loc + contain + LAMBDA_NOOBJ * no + cls;
}

__global__ __launch_bounds__(64) void yolo_cell_kernel(
    const float* __restrict__ pred,
    const float* __restrict__ tgt,
    float* __restrict__ partial)
{
    // double-buffered group staging: 2 x 15360 B
    __shared__ float sbuf[2][GROUP_FLOATS];

    const int lane = threadIdx.x;          // 0..63
    const size_t base_f4 = (size_t)blockIdx.x * GPB * PRED_F4;
    const float4* gp = reinterpret_cast<const float4*>(pred) + base_f4;
    const float4* gt = reinterpret_cast<const float4*>(tgt)  + base_f4;

    // issue 15 fire-and-forget global_load_lds for group g into buffer b
    auto stage = [&](int b, int g) {
        const size_t goff = (size_t)g * PRED_F4;
        #pragma unroll
        for (int k = 0; k < NSTAGE; ++k) {
            const int f = k * 64 + lane;   // combined float4 index [0,960)
            const float4* src = (f < PRED_F4) ? (gp + goff + f)
                                              : (gt + goff + (f - PRED_F4));
            __builtin_amdgcn_global_load_lds(
                (const __attribute__((address_space(1))) void*)src,
                (__attribute__((address_space(3))) void*)&sbuf[b][k * 256],
                16, 0, 0);
        }
    };

    stage(0, 0);

    float acc = 0.0f;
    #pragma unroll
    for (int g = 0; g < GPB; ++g) {
        const int b = g & 1;
        if (g + 1 < GPB) {
            stage(b ^ 1, g + 1);
            // wait for group g's 15 loads; keep the 15 prefetch loads in flight
            asm volatile("s_waitcnt vmcnt(15)" ::: "memory");
        } else {
            asm volatile("s_waitcnt vmcnt(0)" ::: "memory");
        }
        // single-wave block: no barrier needed, LDS is ours alone
        acc += cell_loss(&sbuf[b][lane * NE], &sbuf[b][CPB * NE + lane * NE]);
    }

    // wave shuffle reduction -> one partial per block
    #pragma unroll
    for (int off = 32; off > 0; off >>= 1)
        acc += __shfl_down(acc, off, 64);

    if (lane == 0) partial[blockIdx.x] = acc;
}

__global__ __launch_bounds__(256) void yolo_reduce_kernel(
    const float* __restrict__ partial,
    float* __restrict__ out)
{
    const int tid = threadIdx.x;
    float s = 0.0f;
    #pragma unroll
    for (int i = tid; i < GRID; i += 256)
        s += partial[i];

    #pragma unroll
    for (int off = 32; off > 0; off >>= 1)
        s += __shfl_down(s, off, 64);

    __shared__ float wsum[4];
    const int lane = tid & 63;
    const int wid  = tid >> 6;
    if (lane == 0) wsum[wid] = s;
    __syncthreads();
    if (tid == 0)
        out[0] = wsum[0] + wsum[1] + wsum[2] + wsum[3];
}

extern "C" void kernel_launch(void* const* d_in, const int* in_sizes, int n_in,
                              void* d_out, int out_size, void* d_ws, size_t ws_size,
                              hipStream_t stream) {
    const float* pred = (const float*)d_in[0];
    const float* tgt  = (const float*)d_in[1];
    float* out = (float*)d_out;
    float* partial = (float*)d_ws;          // 1568 floats scratch

    hipLaunchKernelGGL(yolo_cell_kernel, dim3(GRID), dim3(64), 0, stream,
                       pred, tgt, partial);
    hipLaunchKernelGGL(yolo_reduce_kernel, dim3(1), dim3(256), 0, stream,
                       partial, out);
}